// Round 13
// baseline (728.754 us; speedup 1.0000x reference)
//
#include <hip/hip_runtime.h>

// ---------------- problem constants ----------------
constexpr int cB  = 2;
constexpr int cNR = 16384;
constexpr int cNP = 65536;
constexpr int cE  = 262144;
constexpr int cF  = 128;
constexpr int SP  = 136;   // bf16 row stride in LDS (2-way bank aliasing = free)

typedef unsigned short u16;
using f32x4 = __attribute__((ext_vector_type(4))) float;
using s8v   = __attribute__((ext_vector_type(8))) short;

// ws layout (float offsets): agg bf16 [B][NP][128], cnt f32 [B][NP], ss,
// swizzled weights (SWZ_N uint4), rnode_bf16. ~43 MB total.
constexpr size_t WS_CNT = ((size_t)cB * cNP * cF) / 2;
constexpr size_t WS_SS  = WS_CNT + (size_t)cB * cNP;
constexpr size_t WS_WB  = WS_SS + 3 * cB * 256;

constexpr int G8_We2 = 0, G8_Wu1 = 16, G8_Wu2 = 64, G8_Wp1 = 80, G8_Wp2 = 112, G8_Wo1 = 128;
constexpr int G8_TOT = 144;
constexpr int SWZ_N = G8_TOT * 128 + 256;            // uint4 elements (threads)
constexpr size_t WS_RB = WS_WB + (size_t)SWZ_N * 4;  // after SWZ_N*16 bytes

// ---------------- helpers ----------------
__device__ __forceinline__ float bf2f(u16 u) {
  union { unsigned int i; float f; } v; v.i = ((unsigned int)u) << 16; return v.f;
}
__device__ __forceinline__ u16 f2bf(float f) {        // RNE (weights only)
  union { float f; unsigned int i; } v; v.f = f;
  unsigned int x = v.i;
  return (u16)((x + 0x7fffu + ((x >> 16) & 1u)) >> 16);
}
__device__ __forceinline__ u16 f2bf_fast(float f) {
  return (u16)((__float_as_uint(f) + 0x8000u) >> 16);
}
__device__ __forceinline__ unsigned pack2(float a, float b) {
  return __builtin_amdgcn_perm(__float_as_uint(b) + 0x8000u,
                               __float_as_uint(a) + 0x8000u, 0x07060302u);
}
__device__ __forceinline__ float swishf(float x) {
  return x * __builtin_amdgcn_rcpf(1.0f + __expf(-x));
}

// LDS-only barrier: waits LDS ops, NOT outstanding global loads (no vmcnt drain).
// Cross-wave communication in these kernels is exclusively via LDS; per-register
// vmem dependencies are handled by compiler-inserted waitcnts.
__device__ __forceinline__ void lds_barrier() {
  asm volatile("s_waitcnt lgkmcnt(0)\n\ts_barrier" ::: "memory");
}

template <int CTRL>
__device__ __forceinline__ float dpp_add(float x) {
  int xi = __float_as_int(x);
  int r = __builtin_amdgcn_update_dpp(xi, xi, CTRL, 0xf, 0xf, false);
  return x + __int_as_float(r);
}
__device__ __forceinline__ float dpp_xor1(float x) {
  int xi = __float_as_int(x);
  int r = __builtin_amdgcn_update_dpp(xi, xi, 0xB1, 0xf, 0xf, false);
  return __int_as_float(r);
}

__device__ __forceinline__ void atomic_pk_bf16(u16* addr, float lo, float hi) {
  unsigned data = pack2(lo, hi);
  unsigned long long a = (unsigned long long)addr;
  asm volatile("global_atomic_pk_add_bf16 %0, %1, off" :: "v"(a), "v"(data) : "memory");
}

// ---- column-strip MFMA pass: wave covers rows 0..63 x 32-col strip (cw) ----
__device__ __forceinline__ void kloop128s(const u16* act, const u16* __restrict__ wbg,
                                          f32x4 (&acc)[4][2], int cw, int l16, int quad) {
  s8v bf[4][2];
#pragma unroll
  for (int k0 = 0; k0 < 4; ++k0)
#pragma unroll
    for (int ci = 0; ci < 2; ++ci)
      bf[k0][ci] = *(const s8v*)(wbg + ((size_t)(k0 * 4 + quad) * 128 + cw + ci * 16 + l16) * 8);
#pragma unroll
  for (int k0 = 0; k0 < 4; ++k0) {
    s8v af[4];
#pragma unroll
    for (int ri = 0; ri < 4; ++ri)
      af[ri] = *(const s8v*)(act + (size_t)(ri * 16 + l16) * SP + k0 * 32 + quad * 8);
#pragma unroll
    for (int ri = 0; ri < 4; ++ri)
#pragma unroll
      for (int ci = 0; ci < 2; ++ci)
        acc[ri][ci] = __builtin_amdgcn_mfma_f32_16x16x32_bf16(af[ri], bf[k0][ci], acc[ri][ci], 0, 0, 0);
  }
}

__device__ __forceinline__ void init_acc_s(f32x4 (&acc)[4][2], const float* __restrict__ bias,
                                           int cw, int l16) {
#pragma unroll
  for (int ci = 0; ci < 2; ++ci) {
    float bv = bias[cw + ci * 16 + l16];
#pragma unroll
    for (int ri = 0; ri < 4; ++ri) acc[ri][ci] = (f32x4){bv, bv, bv, bv};
  }
}

__device__ __forceinline__ void cond_norm_s(f32x4 (&acc)[4][2], float* red, float* musig,
                                            const float* __restrict__ ssp,
                                            int cw, int l16, int quad, int wv, int t) {
  lds_barrier();                   // prior LDS reads done; red/musig reuse safe
#pragma unroll
  for (int ri = 0; ri < 4; ++ri)
#pragma unroll
    for (int reg = 0; reg < 4; ++reg) {
      float v0 = acc[ri][0][reg], v1 = acc[ri][1][reg];
      float s = v0 + v1;
      float q = v0 * v0 + v1 * v1;
      s = dpp_add<0x128>(s); q = dpp_add<0x128>(q);   // row_ror:8
      s = dpp_add<0x124>(s); q = dpp_add<0x124>(q);   // row_ror:4
      s = dpp_add<0x122>(s); q = dpp_add<0x122>(q);   // row_ror:2
      s = dpp_add<0x121>(s); q = dpp_add<0x121>(q);   // row_ror:1
      if (l16 == 0) {
        int row = ri * 16 + quad * 4 + reg;
        red[row * 8 + wv * 2]     = s;
        red[row * 8 + wv * 2 + 1] = q;
      }
    }
  lds_barrier();
  if (t < 64) {
    float sum = red[t * 8 + 0] + red[t * 8 + 2] + red[t * 8 + 4] + red[t * 8 + 6];
    float sq  = red[t * 8 + 1] + red[t * 8 + 3] + red[t * 8 + 5] + red[t * 8 + 7];
    float mu  = sum * (1.0f / 128.0f);
    float var = fmaxf(sq * (1.0f / 128.0f) - mu * mu, 0.0f);
    musig[t * 2]     = mu;
    musig[t * 2 + 1] = __builtin_amdgcn_rsqf(var + 1e-6f);
  }
  lds_barrier();
  float scl[2], shf[2];
#pragma unroll
  for (int ci = 0; ci < 2; ++ci) {
    int col = cw + ci * 16 + l16;
    scl[ci] = 1.0f + ssp[col];
    shf[ci] = ssp[128 + col];
  }
#pragma unroll
  for (int ri = 0; ri < 4; ++ri)
#pragma unroll
    for (int reg = 0; reg < 4; ++reg) {
      int row = ri * 16 + quad * 4 + reg;
      float mu = musig[row * 2], is = musig[row * 2 + 1];
#pragma unroll
      for (int ci = 0; ci < 2; ++ci)
        acc[ri][ci][reg] = (acc[ri][ci][reg] - mu) * is * scl[ci] + shf[ci];
    }
}

template <bool DOSWISH>
__device__ __forceinline__ void store_s(u16* buf, const f32x4 (&acc)[4][2],
                                        int cw, int l16, int quad) {
#pragma unroll
  for (int ri = 0; ri < 4; ++ri)
#pragma unroll
    for (int reg = 0; reg < 4; ++reg) {
      int row = ri * 16 + quad * 4 + reg;
#pragma unroll
      for (int ci = 0; ci < 2; ++ci) {
        float v = acc[ri][ci][reg];
        if (DOSWISH) v = swishf(v);
        buf[(size_t)row * SP + cw + ci * 16 + l16] = f2bf_fast(v);
      }
    }
}

// ---------------- kernel: zero agg (bf16) + cnt (f32) ----------------
__global__ void zero_kernel(float4* __restrict__ p, int n4) {
  int i = blockIdx.x * 256 + threadIdx.x;
  if (i < n4) p[i] = make_float4(0.f, 0.f, 0.f, 0.f);
}

// ---------------- kernel: rnode f32 -> bf16 copy ----------------
__global__ void cvtn_kernel(const float* __restrict__ src, u16* __restrict__ dst, int n2) {
  int i = blockIdx.x * 256 + threadIdx.x;
  if (i >= n2) return;
  float2 v = ((const float2*)src)[i];
  ((unsigned*)dst)[i] = pack2(v.x, v.y);
}

// ---------------- kernel: weight bf16 swizzle ----------------
struct SwzSrc { const float* p[6]; };  // We2, Wu1, Wu2, Wp1, Wp2, Wo1

__global__ void swz_kernel(SwzSrc s, const float* __restrict__ Wo2, u16* __restrict__ wb) {
  int t = blockIdx.x * 256 + threadIdx.x;
  if (t >= SWZ_N) return;
  if (t >= G8_TOT * 128) {
    int idx2 = t - G8_TOT * 128;
    int k8 = idx2 >> 4, n = idx2 & 15;
    u16 v[8];
#pragma unroll
    for (int j = 0; j < 8; ++j)
      v[j] = (n < 4) ? f2bf(Wo2[(size_t)(k8 * 8 + j) * 4 + n]) : (u16)0;
    ((uint4*)wb)[G8_TOT * 128 + k8 * 16 + n] = *(uint4*)v;
    return;
  }
  int n = t & 127, g8 = t >> 7;
  int seg, base;
  if (g8 < G8_Wu1)      { seg = 0; base = G8_We2; }
  else if (g8 < G8_Wu2) { seg = 1; base = G8_Wu1; }
  else if (g8 < G8_Wp1) { seg = 2; base = G8_Wu2; }
  else if (g8 < G8_Wp2) { seg = 3; base = G8_Wp1; }
  else if (g8 < G8_Wo1) { seg = 4; base = G8_Wp2; }
  else                  { seg = 5; base = G8_Wo1; }
  const float* W = s.p[seg];
  int k8l = g8 - base;
  u16 v[8];
#pragma unroll
  for (int j = 0; j < 8; ++j) v[j] = f2bf(W[(size_t)(k8l * 8 + j) * 128 + n]);
  ((uint4*)wb)[g8 * 128 + n] = *(uint4*)v;
}

// ---------------- kernel: tau-conditioned scale/shift (3 sets) ----------------
__global__ void cond_kernel(const float* __restrict__ tau,
                            const float* __restrict__ Ce1, const float* __restrict__ ce1,
                            const float* __restrict__ Ce2, const float* __restrict__ ce2,
                            const float* __restrict__ Cu1, const float* __restrict__ cu1,
                            const float* __restrict__ Cu2, const float* __restrict__ cu2,
                            const float* __restrict__ Cp1, const float* __restrict__ cp1,
                            const float* __restrict__ Cp2, const float* __restrict__ cp2,
                            float* __restrict__ ss) {
  int set = blockIdx.x, b = blockIdx.y, j = threadIdx.x;
  const float *C1, *c1, *C2, *c2;
  if (set == 0)      { C1 = Ce1; c1 = ce1; C2 = Ce2; c2 = ce2; }
  else if (set == 1) { C1 = Cu1; c1 = cu1; C2 = Cu2; c2 = cu2; }
  else               { C1 = Cp1; c1 = cp1; C2 = Cp2; c2 = cp2; }
  float tf = tau[b];
  float a = c2[j];
  for (int k = 0; k < 16; ++k) {
    float h = swishf(tf * C1[k] + c1[k]);
    a = fmaf(h, C2[k * 256 + j], a);
  }
  ss[(size_t)set * cB * 256 + (size_t)b * 256 + j] = a;
}

// ---------------- fused MFMA edge pipeline: 2 tiles of 64 edges per block ----------------
struct EWb { const float *We1, *be1, *be2, *bu1, *bu2; };

struct __align__(16) EdgeSmem {
  u16 bufE[64 * SP];   // h_embed -> e_emb (current tile)
  u16 bufX[64 * SP];   // sf -> rf -> h2 (current tile)
  float ef4[512];      // edge features for both tiles
  float red[512];
  float musig[128];
  u16 sidx[128], ridx[128];
};  // 39,936 B -> 4 blocks/CU

__device__ __forceinline__ void embed_l1(EdgeSmem& sm, const EWb& w, int io, int t) {
  int col = t & 127, half = t >> 7;
  float w0 = w.We1[col], w1 = w.We1[128 + col], w2 = w.We1[256 + col], w3 = w.We1[384 + col];
  float bb = w.be1[col];
  for (int r = 0; r < 32; ++r) {
    int row = half * 32 + r;
    const float* e4 = sm.ef4 + (io + row) * 4;
    float a = fmaf(e4[3], w3, fmaf(e4[2], w2, fmaf(e4[1], w1, fmaf(e4[0], w0, bb))));
    sm.bufE[(size_t)row * SP + col] = f2bf_fast(swishf(a));
  }
}

// one tile's MFMA pipeline: embed-L2+LN, update-L1 (K=384), update-L2+LN, atomics.
// PRE: at the rf-spill point, prefetch the NEXT tile's rf rows into rfv.
template <bool PRE>
__device__ __forceinline__ void edge_tile(
    EdgeSmem& sm, const EWb& w, const u16* __restrict__ wb,
    const float* __restrict__ ss, u16* __restrict__ aggb,
    const float* __restrict__ pnode, float2 (&rfv)[16], int io, int b,
    int cw, int l16, int quad, int wv, int t, int lane) {
  f32x4 acc[4][2];

  // ---- embed L2 + cond-norm(set0) -> e_emb (bufE) ----
  init_acc_s(acc, w.be2, cw, l16);
  kloop128s(sm.bufE, wb + (size_t)G8_We2 * 1024, acc, cw, l16, quad);
  cond_norm_s(acc, sm.red, sm.musig, ss + (size_t)b * 256, cw, l16, quad, wv, t);
  store_s<false>(sm.bufE, acc, cw, l16, quad);
  lds_barrier();  // e_emb visible

  // ---- update L1: K=384 over [e|sf|rf] ----
  f32x4 accU[4][2];
  init_acc_s(accU, w.bu1, cw, l16);
  kloop128s(sm.bufE, wb + (size_t)G8_Wu1 * 1024, accU, cw, l16, quad);
  kloop128s(sm.bufX, wb + (size_t)(G8_Wu1 + 16) * 1024, accU, cw, l16, quad);
  lds_barrier();  // all waves done reading bufX(sf)

  // spill this tile's rf -> bufX; optionally issue next tile's rf gather
#pragma unroll
  for (int rr = 0; rr < 16; ++rr)
    *(unsigned*)(sm.bufX + (size_t)(wv * 16 + rr) * SP + lane * 2) = pack2(rfv[rr].x, rfv[rr].y);
  if (PRE) {
#pragma unroll
    for (int rr = 0; rr < 16; ++rr) {
      int row = wv * 16 + rr;
      rfv[rr] = *(const float2*)(pnode + ((size_t)b * cNP + sm.ridx[64 + row]) * cF + lane * 2);
    }
  }
  lds_barrier();  // bufX(rf) visible

  kloop128s(sm.bufX, wb + (size_t)(G8_Wu1 + 32) * 1024, accU, cw, l16, quad);
  lds_barrier();  // all waves done reading bufX(rf)
  store_s<true>(sm.bufX, accU, cw, l16, quad);  // h2
  lds_barrier();  // h2 visible

  // ---- update L2 + cond-norm(set1) ----
  init_acc_s(acc, w.bu2, cw, l16);
  kloop128s(sm.bufX, wb + (size_t)G8_Wu2 * 1024, acc, cw, l16, quad);
  cond_norm_s(acc, sm.red, sm.musig, ss + (size_t)(cB + b) * 256, cw, l16, quad, wv, t);

  // e = e_emb + u ; packed-bf16 segment-sum atomics
#pragma unroll
  for (int ri = 0; ri < 4; ++ri)
#pragma unroll
    for (int reg = 0; reg < 4; ++reg) {
      int row = ri * 16 + quad * 4 + reg;
      size_t rbase = ((size_t)b * cNP + sm.ridx[io + row]) * cF;
#pragma unroll
      for (int ci = 0; ci < 2; ++ci) {
        int col = cw + ci * 16 + l16;
        float v = acc[ri][ci][reg] + bf2f(sm.bufE[(size_t)row * SP + col]);
        float vo = dpp_xor1(v);
        if (!(lane & 1)) atomic_pk_bf16(aggb + rbase + col, v, vo);
      }
    }
}

__global__ __launch_bounds__(256, 4) void edge_mfma(
    const u16* __restrict__ rnb, const float* __restrict__ pnode,
    const float* __restrict__ efeat, const int* __restrict__ senders,
    const int* __restrict__ receivers, EWb w, const u16* __restrict__ wb,
    const float* __restrict__ ss, u16* __restrict__ aggb, float* __restrict__ cnt) {
  __shared__ EdgeSmem sm;
  const int t = threadIdx.x, wv = t >> 6, lane = t & 63, l16 = lane & 15, quad = lane >> 4;
  const int cw = wv * 32;
  const int b  = blockIdx.y;
  const int e0 = blockIdx.x * 128;   // two tiles

  if (t < 128) {
    sm.sidx[t] = (u16)min(max(senders[(size_t)b * cE + e0 + t], 0), cNR - 1);
    sm.ridx[t] = (u16)min(max(receivers[(size_t)b * cE + e0 + t], 0), cNP - 1);
  }
  ((float2*)sm.ef4)[t] = ((const float2*)(efeat + ((size_t)b * cE + e0) * 4))[t];
  lds_barrier();  // idx + ef4 visible

  // tile0 gathers: sf0 -> bufX, rf0 -> rfv regs; tile1 sf -> sfp1 regs (prefetch)
  float2 rfv[16];
  unsigned sfp1[16];
#pragma unroll
  for (int rr = 0; rr < 16; ++rr) {
    int row = wv * 16 + rr;
    unsigned sv = *(const unsigned*)(rnb + ((size_t)b * cNR + sm.sidx[row]) * cF + lane * 2);
    rfv[rr] = *(const float2*)(pnode + ((size_t)b * cNP + sm.ridx[row]) * cF + lane * 2);
    sfp1[rr] = *(const unsigned*)(rnb + ((size_t)b * cNR + sm.sidx[64 + row]) * cF + lane * 2);
    *(unsigned*)(sm.bufX + (size_t)row * SP + lane * 2) = sv;
  }
  embed_l1(sm, w, 0, t);
  lds_barrier();  // bufE(h_embed0) + bufX(sf0) visible

  edge_tile<true>(sm, w, wb, ss, aggb, pnode, rfv, 0, b, cw, l16, quad, wv, t, lane);

  if (t < 128) atomicAdd(cnt + (size_t)b * cNP + sm.ridx[t], 1.0f);  // both tiles
  lds_barrier();  // all waves done reading tile0's bufE/bufX

  // tile1 staging: sf1 (prefetched regs) -> bufX; embed L1 tile1 -> bufE
#pragma unroll
  for (int rr = 0; rr < 16; ++rr)
    *(unsigned*)(sm.bufX + (size_t)(wv * 16 + rr) * SP + lane * 2) = sfp1[rr];
  embed_l1(sm, w, 64, t);
  lds_barrier();

  edge_tile<false>(sm, w, wb, ss, aggb, pnode, rfv, 64, b, cw, l16, quad, wv, t, lane);
}

// ---------------- fused MFMA pnode pipeline (both batches), M=64 nodes/block ----------------
struct PWb { const float *bp1, *bp2, *bo1, *bo2; };

struct __align__(16) PnodeSmem {
  u16 bufP[64 * SP];
  u16 bufX[64 * SP];
  float red[512];
  float musig[128];
  float cinv[64];
};

__global__ __launch_bounds__(256, 4) void pnode_mfma(
    const float* __restrict__ pnode, PWb w, const u16* __restrict__ wb,
    const float* __restrict__ ss, const u16* __restrict__ aggb,
    const float* __restrict__ cnt, float* __restrict__ out) {
  __shared__ PnodeSmem sm;
  const int t = threadIdx.x, wv = t >> 6, lane = t & 63, l16 = lane & 15, quad = lane >> 4;
  const int cw = wv * 32;
  const int b  = blockIdx.y;
  const int n0 = blockIdx.x * 64;

  if (t < 64) sm.cinv[t] = __builtin_amdgcn_rcpf(fmaxf(cnt[(size_t)b * cNP + n0 + t], 1.0f));
  lds_barrier();

#pragma unroll
  for (int rr = 0; rr < 16; ++rr) {
    int row = wv * 16 + rr;
    float2 pv = *(const float2*)(pnode + ((size_t)b * cNP + n0 + row) * cF + lane * 2);
    unsigned avu = *(const unsigned*)(aggb + (((size_t)b * cNP + n0 + row) * cF + lane * 2));
    float ci_ = sm.cinv[row];
    float a0 = bf2f((u16)(avu & 0xffffu)) * ci_;
    float a1 = bf2f((u16)(avu >> 16)) * ci_;
    *(unsigned*)(sm.bufP + (size_t)row * SP + lane * 2) = pack2(pv.x, pv.y);
    *(unsigned*)(sm.bufX + (size_t)row * SP + lane * 2) = pack2(a0, a1);
  }
  lds_barrier();

  f32x4 acc[4][2];

  // ---- pnode L1: K=256 over [pf|mean] ----
  init_acc_s(acc, w.bp1, cw, l16);
  kloop128s(sm.bufP, wb + (size_t)G8_Wp1 * 1024, acc, cw, l16, quad);
  kloop128s(sm.bufX, wb + (size_t)(G8_Wp1 + 16) * 1024, acc, cw, l16, quad);
  lds_barrier();
  store_s<true>(sm.bufX, acc, cw, l16, quad);  // h1
  lds_barrier();

  // ---- pnode L2 + cond-norm(set2) + residual -> bufP ----
  init_acc_s(acc, w.bp2, cw, l16);
  kloop128s(sm.bufX, wb + (size_t)G8_Wp2 * 1024, acc, cw, l16, quad);
  cond_norm_s(acc, sm.red, sm.musig, ss + (size_t)(2 * cB + b) * 256, cw, l16, quad, wv, t);
#pragma unroll
  for (int ri = 0; ri < 4; ++ri)
#pragma unroll
    for (int reg = 0; reg < 4; ++reg) {
      int row = ri * 16 + quad * 4 + reg;
#pragma unroll
      for (int ci = 0; ci < 2; ++ci)
        acc[ri][ci][reg] += bf2f(sm.bufP[(size_t)row * SP + cw + ci * 16 + l16]);
    }
  lds_barrier();
  store_s<false>(sm.bufP, acc, cw, l16, quad);  // p_new
  lds_barrier();

  // ---- output L1: K=128 -> bufX ----
  init_acc_s(acc, w.bo1, cw, l16);
  kloop128s(sm.bufP, wb + (size_t)G8_Wo1 * 1024, acc, cw, l16, quad);
  store_s<true>(sm.bufX, acc, cw, l16, quad);
  lds_barrier();

  // ---- output L2 via MFMA: K=128, N=16 (4 used); wave wv owns rows wv*16..+15 ----
  {
    const u16* wo2 = wb + (size_t)G8_TOT * 1024;
    float bv = (l16 < 4) ? w.bo2[l16] : 0.0f;
    f32x4 a1 = {bv, bv, bv, bv};
#pragma unroll
    for (int k0 = 0; k0 < 4; ++k0) {
      s8v af = *(const s8v*)(sm.bufX + (size_t)(wv * 16 + l16) * SP + k0 * 32 + quad * 8);
      s8v bf = *(const s8v*)(wo2 + ((size_t)(k0 * 4 + quad) * 16 + l16) * 8);
      a1 = __builtin_amdgcn_mfma_f32_16x16x32_bf16(af, bf, a1, 0, 0, 0);
    }
    if (l16 < 4) {
      size_t obase = (size_t)b * cNP + n0 + wv * 16 + quad * 4;
#pragma unroll
      for (int reg = 0; reg < 4; ++reg)
        out[(obase + reg) * 4 + l16] = a1[reg];
    }
  }
}

// ---------------- launch ----------------
extern "C" void kernel_launch(void* const* d_in, const int* in_sizes, int n_in,
                              void* d_out, int out_size, void* d_ws, size_t ws_size,
                              hipStream_t stream) {
  const float* rnode = (const float*)d_in[0];
  const float* pnode = (const float*)d_in[1];
  const float* efeat = (const float*)d_in[2];
  const float* tau   = (const float*)d_in[3];
  const int* senders   = (const int*)d_in[40];
  const int* receivers = (const int*)d_in[41];
  float* ws = (float*)d_ws;
  u16* aggb = (u16*)d_ws;
  u16* wb   = (u16*)(ws + WS_WB);
  u16* rnb  = (u16*)(ws + WS_RB);

  SwzSrc sw;
  sw.p[0] = (const float*)d_in[5];   // We2
  sw.p[1] = (const float*)d_in[12];  // Wu1
  sw.p[2] = (const float*)d_in[13];  // Wu2
  sw.p[3] = (const float*)d_in[20];  // Wp1
  sw.p[4] = (const float*)d_in[21];  // Wp2
  sw.p[5] = (const float*)d_in[36];  // Wo1
  swz_kernel<<<(SWZ_N + 255) / 256, 256, 0, stream>>>(sw, (const float*)d_in[37], wb);

  const int nrn2 = (int)((size_t)cB * cNR * cF / 2);
  cvtn_kernel<<<(nrn2 + 255) / 256, 256, 0, stream>>>(rnode, rnb, nrn2);

  cond_kernel<<<dim3(3, cB), 256, 0, stream>>>(
      tau,
      (const float*)d_in[8],  (const float*)d_in[10],
      (const float*)d_in[9],  (const float*)d_in[11],
      (const float*)d_in[16], (const float*)d_in[18],
      (const float*)d_in[17], (const float*)d_in[19],
      (const float*)d_in[24], (const float*)d_in[26],
      (const float*)d_in[25], (const float*)d_in[27],
      ws + WS_SS);

  EWb ew = { (const float*)d_in[4], (const float*)d_in[6], (const float*)d_in[7],
             (const float*)d_in[14], (const float*)d_in[15] };
  PWb pw = { (const float*)d_in[22], (const float*)d_in[23], (const float*)d_in[38],
             (const float*)d_in[39] };

  const int n4 = (int)(WS_SS / 4);
  zero_kernel<<<(n4 + 255) / 256, 256, 0, stream>>>((float4*)ws, n4);

  edge_mfma<<<dim3(cE / 128, cB), 256, 0, stream>>>(
      rnb, pnode, efeat, senders, receivers, ew, wb,
      ws + WS_SS, aggb, ws + WS_CNT);

  pnode_mfma<<<dim3(cNP / 64, cB), 256, 0, stream>>>(
      pnode, pw, wb, ws + WS_SS, aggb, ws + WS_CNT,
      (float*)d_out);
}

// Round 14
// 569.881 us; speedup vs baseline: 1.2788x; 1.2788x over previous
//
#include <hip/hip_runtime.h>

// ---------------- problem constants ----------------
constexpr int cB  = 2;
constexpr int cNR = 16384;
constexpr int cNP = 65536;
constexpr int cE  = 262144;
constexpr int cF  = 128;
constexpr int SP  = 136;   // bf16 row stride in LDS (2-way bank aliasing = free)

typedef unsigned short u16;
using f32x4 = __attribute__((ext_vector_type(4))) float;
using s8v   = __attribute__((ext_vector_type(8))) short;

// ws layout (float offsets): agg bf16 [B][NP][128], cnt f32 [B][NP], ss,
// swizzled weights (SWZ_N uint4), rnode_bf16. ~43 MB total.
constexpr size_t WS_CNT = ((size_t)cB * cNP * cF) / 2;
constexpr size_t WS_SS  = WS_CNT + (size_t)cB * cNP;
constexpr size_t WS_WB  = WS_SS + 3 * cB * 256;

constexpr int G8_We2 = 0, G8_Wu1 = 16, G8_Wu2 = 64, G8_Wp1 = 80, G8_Wp2 = 112, G8_Wo1 = 128;
constexpr int G8_TOT = 144;
constexpr int SWZ_N = G8_TOT * 128 + 256;            // uint4 elements (threads)
constexpr size_t WS_RB = WS_WB + (size_t)SWZ_N * 4;  // after SWZ_N*16 bytes

// ---------------- helpers ----------------
__device__ __forceinline__ float bf2f(u16 u) {
  union { unsigned int i; float f; } v; v.i = ((unsigned int)u) << 16; return v.f;
}
__device__ __forceinline__ u16 f2bf(float f) {        // RNE (weights only)
  union { float f; unsigned int i; } v; v.f = f;
  unsigned int x = v.i;
  return (u16)((x + 0x7fffu + ((x >> 16) & 1u)) >> 16);
}
__device__ __forceinline__ u16 f2bf_fast(float f) {
  return (u16)((__float_as_uint(f) + 0x8000u) >> 16);
}
__device__ __forceinline__ unsigned pack2(float a, float b) {
  return __builtin_amdgcn_perm(__float_as_uint(b) + 0x8000u,
                               __float_as_uint(a) + 0x8000u, 0x07060302u);
}
__device__ __forceinline__ float swishf(float x) {
  return x * __builtin_amdgcn_rcpf(1.0f + __expf(-x));
}

// LDS-only barrier: waits LDS ops, NOT outstanding global loads/atomics (no
// vmcnt drain). Cross-wave communication in these kernels is exclusively via
// LDS; per-register vmem dependencies get compiler-inserted waitcnts.
__device__ __forceinline__ void lds_barrier() {
  asm volatile("s_waitcnt lgkmcnt(0)\n\ts_barrier" ::: "memory");
}

template <int CTRL>
__device__ __forceinline__ float dpp_add(float x) {
  int xi = __float_as_int(x);
  int r = __builtin_amdgcn_update_dpp(xi, xi, CTRL, 0xf, 0xf, false);
  return x + __int_as_float(r);
}
__device__ __forceinline__ float dpp_xor1(float x) {
  int xi = __float_as_int(x);
  int r = __builtin_amdgcn_update_dpp(xi, xi, 0xB1, 0xf, 0xf, false);
  return __int_as_float(r);
}

__device__ __forceinline__ void atomic_pk_bf16(u16* addr, float lo, float hi) {
  unsigned data = pack2(lo, hi);
  unsigned long long a = (unsigned long long)addr;
  asm volatile("global_atomic_pk_add_bf16 %0, %1, off" :: "v"(a), "v"(data) : "memory");
}

// ---- column-strip MFMA pass: wave covers rows 0..63 x 32-col strip (cw) ----
__device__ __forceinline__ void kloop128s(const u16* act, const u16* __restrict__ wbg,
                                          f32x4 (&acc)[4][2], int cw, int l16, int quad) {
  s8v bf[4][2];
#pragma unroll
  for (int k0 = 0; k0 < 4; ++k0)
#pragma unroll
    for (int ci = 0; ci < 2; ++ci)
      bf[k0][ci] = *(const s8v*)(wbg + ((size_t)(k0 * 4 + quad) * 128 + cw + ci * 16 + l16) * 8);
#pragma unroll
  for (int k0 = 0; k0 < 4; ++k0) {
    s8v af[4];
#pragma unroll
    for (int ri = 0; ri < 4; ++ri)
      af[ri] = *(const s8v*)(act + (size_t)(ri * 16 + l16) * SP + k0 * 32 + quad * 8);
#pragma unroll
    for (int ri = 0; ri < 4; ++ri)
#pragma unroll
      for (int ci = 0; ci < 2; ++ci)
        acc[ri][ci] = __builtin_amdgcn_mfma_f32_16x16x32_bf16(af[ri], bf[k0][ci], acc[ri][ci], 0, 0, 0);
  }
}

__device__ __forceinline__ void init_acc_s(f32x4 (&acc)[4][2], const float* __restrict__ bias,
                                           int cw, int l16) {
#pragma unroll
  for (int ci = 0; ci < 2; ++ci) {
    float bv = bias[cw + ci * 16 + l16];
#pragma unroll
    for (int ri = 0; ri < 4; ++ri) acc[ri][ci] = (f32x4){bv, bv, bv, bv};
  }
}

// conditioned LayerNorm on strip C-layout; 16-lane reduce via DPP row_ror (VALU only)
__device__ __forceinline__ void cond_norm_s(f32x4 (&acc)[4][2], float* red, float* musig,
                                            const float* __restrict__ ssp,
                                            int cw, int l16, int quad, int wv, int t) {
  lds_barrier();                   // prior LDS reads done; red/musig reuse safe
#pragma unroll
  for (int ri = 0; ri < 4; ++ri)
#pragma unroll
    for (int reg = 0; reg < 4; ++reg) {
      float v0 = acc[ri][0][reg], v1 = acc[ri][1][reg];
      float s = v0 + v1;
      float q = v0 * v0 + v1 * v1;
      s = dpp_add<0x128>(s); q = dpp_add<0x128>(q);   // row_ror:8
      s = dpp_add<0x124>(s); q = dpp_add<0x124>(q);   // row_ror:4
      s = dpp_add<0x122>(s); q = dpp_add<0x122>(q);   // row_ror:2
      s = dpp_add<0x121>(s); q = dpp_add<0x121>(q);   // row_ror:1
      if (l16 == 0) {
        int row = ri * 16 + quad * 4 + reg;
        red[row * 8 + wv * 2]     = s;
        red[row * 8 + wv * 2 + 1] = q;
      }
    }
  lds_barrier();
  if (t < 64) {
    float sum = red[t * 8 + 0] + red[t * 8 + 2] + red[t * 8 + 4] + red[t * 8 + 6];
    float sq  = red[t * 8 + 1] + red[t * 8 + 3] + red[t * 8 + 5] + red[t * 8 + 7];
    float mu  = sum * (1.0f / 128.0f);
    float var = fmaxf(sq * (1.0f / 128.0f) - mu * mu, 0.0f);
    musig[t * 2]     = mu;
    musig[t * 2 + 1] = __builtin_amdgcn_rsqf(var + 1e-6f);
  }
  lds_barrier();
  float scl[2], shf[2];
#pragma unroll
  for (int ci = 0; ci < 2; ++ci) {
    int col = cw + ci * 16 + l16;
    scl[ci] = 1.0f + ssp[col];
    shf[ci] = ssp[128 + col];
  }
#pragma unroll
  for (int ri = 0; ri < 4; ++ri)
#pragma unroll
    for (int reg = 0; reg < 4; ++reg) {
      int row = ri * 16 + quad * 4 + reg;
      float mu = musig[row * 2], is = musig[row * 2 + 1];
#pragma unroll
      for (int ci = 0; ci < 2; ++ci)
        acc[ri][ci][reg] = (acc[ri][ci][reg] - mu) * is * scl[ci] + shf[ci];
    }
}

template <bool DOSWISH>
__device__ __forceinline__ void store_s(u16* buf, const f32x4 (&acc)[4][2],
                                        int cw, int l16, int quad) {
#pragma unroll
  for (int ri = 0; ri < 4; ++ri)
#pragma unroll
    for (int reg = 0; reg < 4; ++reg) {
      int row = ri * 16 + quad * 4 + reg;
#pragma unroll
      for (int ci = 0; ci < 2; ++ci) {
        float v = acc[ri][ci][reg];
        if (DOSWISH) v = swishf(v);
        buf[(size_t)row * SP + cw + ci * 16 + l16] = f2bf_fast(v);
      }
    }
}

// ---------------- kernel: zero agg (bf16) + cnt (f32) ----------------
__global__ void zero_kernel(float4* __restrict__ p, int n4) {
  int i = blockIdx.x * 256 + threadIdx.x;
  if (i < n4) p[i] = make_float4(0.f, 0.f, 0.f, 0.f);
}

// ---------------- kernel: rnode f32 -> bf16 copy ----------------
__global__ void cvtn_kernel(const float* __restrict__ src, u16* __restrict__ dst, int n2) {
  int i = blockIdx.x * 256 + threadIdx.x;
  if (i >= n2) return;
  float2 v = ((const float2*)src)[i];
  ((unsigned*)dst)[i] = pack2(v.x, v.y);
}

// ---------------- kernel: weight bf16 swizzle ----------------
struct SwzSrc { const float* p[6]; };  // We2, Wu1, Wu2, Wp1, Wp2, Wo1

__global__ void swz_kernel(SwzSrc s, const float* __restrict__ Wo2, u16* __restrict__ wb) {
  int t = blockIdx.x * 256 + threadIdx.x;
  if (t >= SWZ_N) return;
  if (t >= G8_TOT * 128) {
    int idx2 = t - G8_TOT * 128;
    int k8 = idx2 >> 4, n = idx2 & 15;
    u16 v[8];
#pragma unroll
    for (int j = 0; j < 8; ++j)
      v[j] = (n < 4) ? f2bf(Wo2[(size_t)(k8 * 8 + j) * 4 + n]) : (u16)0;
    ((uint4*)wb)[G8_TOT * 128 + k8 * 16 + n] = *(uint4*)v;
    return;
  }
  int n = t & 127, g8 = t >> 7;
  int seg, base;
  if (g8 < G8_Wu1)      { seg = 0; base = G8_We2; }
  else if (g8 < G8_Wu2) { seg = 1; base = G8_Wu1; }
  else if (g8 < G8_Wp1) { seg = 2; base = G8_Wu2; }
  else if (g8 < G8_Wp2) { seg = 3; base = G8_Wp1; }
  else if (g8 < G8_Wo1) { seg = 4; base = G8_Wp2; }
  else                  { seg = 5; base = G8_Wo1; }
  const float* W = s.p[seg];
  int k8l = g8 - base;
  u16 v[8];
#pragma unroll
  for (int j = 0; j < 8; ++j) v[j] = f2bf(W[(size_t)(k8l * 8 + j) * 128 + n]);
  ((uint4*)wb)[g8 * 128 + n] = *(uint4*)v;
}

// ---------------- kernel: tau-conditioned scale/shift (3 sets) ----------------
__global__ void cond_kernel(const float* __restrict__ tau,
                            const float* __restrict__ Ce1, const float* __restrict__ ce1,
                            const float* __restrict__ Ce2, const float* __restrict__ ce2,
                            const float* __restrict__ Cu1, const float* __restrict__ cu1,
                            const float* __restrict__ Cu2, const float* __restrict__ cu2,
                            const float* __restrict__ Cp1, const float* __restrict__ cp1,
                            const float* __restrict__ Cp2, const float* __restrict__ cp2,
                            float* __restrict__ ss) {
  int set = blockIdx.x, b = blockIdx.y, j = threadIdx.x;
  const float *C1, *c1, *C2, *c2;
  if (set == 0)      { C1 = Ce1; c1 = ce1; C2 = Ce2; c2 = ce2; }
  else if (set == 1) { C1 = Cu1; c1 = cu1; C2 = Cu2; c2 = cu2; }
  else               { C1 = Cp1; c1 = cp1; C2 = Cp2; c2 = cp2; }
  float tf = tau[b];
  float a = c2[j];
  for (int k = 0; k < 16; ++k) {
    float h = swishf(tf * C1[k] + c1[k]);
    a = fmaf(h, C2[k * 256 + j], a);
  }
  ss[(size_t)set * cB * 256 + (size_t)b * 256 + j] = a;
}

// ---------------- fused MFMA edge pipeline (both batches), M=64 edges/block ----------------
struct EWb { const float *We1, *be1, *be2, *bu1, *bu2; };

struct __align__(16) EdgeSmem {
  u16 bufE[64 * SP];   // h_embed -> e_emb (kept for final residual)
  u16 bufX[64 * SP];   // sf -> rf -> h2
  float ef4[256];
  float red[512];
  float musig[128];
  int sidx[64], ridx[64];
};  // ~38.9 KB -> 4 blocks/CU

__global__ __launch_bounds__(256, 4) void edge_mfma(
    const u16* __restrict__ rnb, const float* __restrict__ pnode,
    const float* __restrict__ efeat, const int* __restrict__ senders,
    const int* __restrict__ receivers, EWb w, const u16* __restrict__ wb,
    const float* __restrict__ ss, u16* __restrict__ aggb, float* __restrict__ cnt) {
  __shared__ EdgeSmem sm;
  const int t = threadIdx.x, wv = t >> 6, lane = t & 63, l16 = lane & 15, quad = lane >> 4;
  const int cw = wv * 32;          // column strip base
  const int b  = blockIdx.y;
  const int e0 = blockIdx.x * 64;

  if (t < 64) {
    sm.sidx[t] = min(max(senders[(size_t)b * cE + e0 + t], 0), cNR - 1);
    sm.ridx[t] = min(max(receivers[(size_t)b * cE + e0 + t], 0), cNP - 1);
  } else if (t >= 128) {
    ((float2*)sm.ef4)[t - 128] = ((const float2*)(efeat + ((size_t)b * cE + e0) * 4))[t - 128];
  }
  lds_barrier();  // b1

  // gather sf (bf16 pre-converted, u32 copy) -> bufX; rf -> registers
  unsigned rfp[16];
#pragma unroll
  for (int rr = 0; rr < 16; ++rr) {
    int row = wv * 16 + rr;
    unsigned sv = *(const unsigned*)(rnb + ((size_t)b * cNR + sm.sidx[row]) * cF + lane * 2);
    float2 rv = *(const float2*)(pnode + ((size_t)b * cNP + sm.ridx[row]) * cF + lane * 2);
    *(unsigned*)(sm.bufX + (size_t)row * SP + lane * 2) = sv;
    rfp[rr] = pack2(rv.x, rv.y);
  }

  // embed layer 1 (K=4, VALU) -> bufE
  {
    int col = t & 127, half = t >> 7;
    float w0 = w.We1[col], w1 = w.We1[128 + col], w2 = w.We1[256 + col], w3 = w.We1[384 + col];
    float bb = w.be1[col];
    for (int r = 0; r < 32; ++r) {
      int row = half * 32 + r;
      float a = fmaf(sm.ef4[row * 4 + 3], w3, fmaf(sm.ef4[row * 4 + 2], w2,
                fmaf(sm.ef4[row * 4 + 1], w1, fmaf(sm.ef4[row * 4 + 0], w0, bb))));
      sm.bufE[(size_t)row * SP + col] = f2bf_fast(swishf(a));
    }
  }
  lds_barrier();  // b2: bufE(h_embed) + bufX(sf) visible

  f32x4 acc[4][2];

  // ---- embed L2 + cond-norm(set0) -> e_emb (bufE) ----
  init_acc_s(acc, w.be2, cw, l16);
  kloop128s(sm.bufE, wb + (size_t)G8_We2 * 1024, acc, cw, l16, quad);
  cond_norm_s(acc, sm.red, sm.musig, ss + (size_t)b * 256, cw, l16, quad, wv, t);
  store_s<false>(sm.bufE, acc, cw, l16, quad);
  lds_barrier();  // b3: e_emb visible

  // ---- update L1: K=384 over [e|sf|rf] ----
  f32x4 accU[4][2];
  init_acc_s(accU, w.bu1, cw, l16);
  kloop128s(sm.bufE, wb + (size_t)G8_Wu1 * 1024, accU, cw, l16, quad);
  kloop128s(sm.bufX, wb + (size_t)(G8_Wu1 + 16) * 1024, accU, cw, l16, quad);
  lds_barrier();  // b4: all waves done reading bufX(sf)

  // spill prefetched rf regs -> bufX
#pragma unroll
  for (int rr = 0; rr < 16; ++rr)
    *(unsigned*)(sm.bufX + (size_t)(wv * 16 + rr) * SP + lane * 2) = rfp[rr];
  lds_barrier();  // b5: bufX(rf) visible

  kloop128s(sm.bufX, wb + (size_t)(G8_Wu1 + 32) * 1024, accU, cw, l16, quad);
  lds_barrier();  // b6: all waves done reading bufX(rf)
  store_s<true>(sm.bufX, accU, cw, l16, quad);  // h2
  lds_barrier();  // b7: h2 visible

  // ---- update L2 + cond-norm(set1) ----
  init_acc_s(acc, w.bu2, cw, l16);
  kloop128s(sm.bufX, wb + (size_t)G8_Wu2 * 1024, acc, cw, l16, quad);
  cond_norm_s(acc, sm.red, sm.musig, ss + (size_t)(cB + b) * 256, cw, l16, quad, wv, t);

  // e = e_emb + u ; packed-bf16 segment-sum atomics (even lane pairs with odd via DPP)
#pragma unroll
  for (int ri = 0; ri < 4; ++ri)
#pragma unroll
    for (int reg = 0; reg < 4; ++reg) {
      int row = ri * 16 + quad * 4 + reg;
      size_t rbase = ((size_t)b * cNP + sm.ridx[row]) * cF;
#pragma unroll
      for (int ci = 0; ci < 2; ++ci) {
        int col = cw + ci * 16 + l16;
        float v = acc[ri][ci][reg] + bf2f(sm.bufE[(size_t)row * SP + col]);
        float vo = dpp_xor1(v);
        if (!(lane & 1)) atomic_pk_bf16(aggb + rbase + col, v, vo);
      }
    }
  if (t < 64) atomicAdd(cnt + (size_t)b * cNP + sm.ridx[t], 1.0f);
}

// ---------------- fused MFMA pnode pipeline (both batches), M=64 nodes/block ----------------
struct PWb { const float *bp1, *bp2, *bo1, *bo2; };

struct __align__(16) PnodeSmem {
  u16 bufP[64 * SP];
  u16 bufX[64 * SP];
  float red[512];
  float musig[128];
  float cinv[64];
};

__global__ __launch_bounds__(256, 4) void pnode_mfma(
    const float* __restrict__ pnode, PWb w, const u16* __restrict__ wb,
    const float* __restrict__ ss, const u16* __restrict__ aggb,
    const float* __restrict__ cnt, float* __restrict__ out) {
  __shared__ PnodeSmem sm;
  const int t = threadIdx.x, wv = t >> 6, lane = t & 63, l16 = lane & 15, quad = lane >> 4;
  const int cw = wv * 32;
  const int b  = blockIdx.y;
  const int n0 = blockIdx.x * 64;

  if (t < 64) sm.cinv[t] = __builtin_amdgcn_rcpf(fmaxf(cnt[(size_t)b * cNP + n0 + t], 1.0f));
  lds_barrier();  // b1

#pragma unroll
  for (int rr = 0; rr < 16; ++rr) {
    int row = wv * 16 + rr;
    float2 pv = *(const float2*)(pnode + ((size_t)b * cNP + n0 + row) * cF + lane * 2);
    unsigned avu = *(const unsigned*)(aggb + (((size_t)b * cNP + n0 + row) * cF + lane * 2));
    float ci_ = sm.cinv[row];
    float a0 = bf2f((u16)(avu & 0xffffu)) * ci_;
    float a1 = bf2f((u16)(avu >> 16)) * ci_;
    *(unsigned*)(sm.bufP + (size_t)row * SP + lane * 2) = pack2(pv.x, pv.y);
    *(unsigned*)(sm.bufX + (size_t)row * SP + lane * 2) = pack2(a0, a1);
  }
  lds_barrier();  // b2

  f32x4 acc[4][2];

  // ---- pnode L1: K=256 over [pf|mean] ----
  init_acc_s(acc, w.bp1, cw, l16);
  kloop128s(sm.bufP, wb + (size_t)G8_Wp1 * 1024, acc, cw, l16, quad);
  kloop128s(sm.bufX, wb + (size_t)(G8_Wp1 + 16) * 1024, acc, cw, l16, quad);
  lds_barrier();  // b3
  store_s<true>(sm.bufX, acc, cw, l16, quad);  // h1
  lds_barrier();  // b4

  // ---- pnode L2 + cond-norm(set2) + residual -> bufP ----
  init_acc_s(acc, w.bp2, cw, l16);
  kloop128s(sm.bufX, wb + (size_t)G8_Wp2 * 1024, acc, cw, l16, quad);
  cond_norm_s(acc, sm.red, sm.musig, ss + (size_t)(2 * cB + b) * 256, cw, l16, quad, wv, t);
#pragma unroll
  for (int ri = 0; ri < 4; ++ri)
#pragma unroll
    for (int reg = 0; reg < 4; ++reg) {
      int row = ri * 16 + quad * 4 + reg;
#pragma unroll
      for (int ci = 0; ci < 2; ++ci)
        acc[ri][ci][reg] += bf2f(sm.bufP[(size_t)row * SP + cw + ci * 16 + l16]);
    }
  lds_barrier();  // b5
  store_s<false>(sm.bufP, acc, cw, l16, quad);  // p_new
  lds_barrier();  // b6

  // ---- output L1: K=128 -> bufX ----
  init_acc_s(acc, w.bo1, cw, l16);
  kloop128s(sm.bufP, wb + (size_t)G8_Wo1 * 1024, acc, cw, l16, quad);
  store_s<true>(sm.bufX, acc, cw, l16, quad);
  lds_barrier();  // b7

  // ---- output L2 via MFMA: K=128, N=16 (4 used); wave wv owns rows wv*16..+15 ----
  {
    const u16* wo2 = wb + (size_t)G8_TOT * 1024;
    float bv = (l16 < 4) ? w.bo2[l16] : 0.0f;
    f32x4 a1 = {bv, bv, bv, bv};
#pragma unroll
    for (int k0 = 0; k0 < 4; ++k0) {
      s8v af = *(const s8v*)(sm.bufX + (size_t)(wv * 16 + l16) * SP + k0 * 32 + quad * 8);
      s8v bf = *(const s8v*)(wo2 + ((size_t)(k0 * 4 + quad) * 16 + l16) * 8);
      a1 = __builtin_amdgcn_mfma_f32_16x16x32_bf16(af, bf, a1, 0, 0, 0);
    }
    if (l16 < 4) {
      size_t obase = (size_t)b * cNP + n0 + wv * 16 + quad * 4;
#pragma unroll
      for (int reg = 0; reg < 4; ++reg)
        out[(obase + reg) * 4 + l16] = a1[reg];
    }
  }
}

// ---------------- launch ----------------
extern "C" void kernel_launch(void* const* d_in, const int* in_sizes, int n_in,
                              void* d_out, int out_size, void* d_ws, size_t ws_size,
                              hipStream_t stream) {
  const float* rnode = (const float*)d_in[0];
  const float* pnode = (const float*)d_in[1];
  const float* efeat = (const float*)d_in[2];
  const float* tau   = (const float*)d_in[3];
  const int* senders   = (const int*)d_in[40];
  const int* receivers = (const int*)d_in[41];
  float* ws = (float*)d_ws;
  u16* aggb = (u16*)d_ws;
  u16* wb   = (u16*)(ws + WS_WB);
  u16* rnb  = (u16*)(ws + WS_RB);

  SwzSrc sw;
  sw.p[0] = (const float*)d_in[5];   // We2
  sw.p[1] = (const float*)d_in[12];  // Wu1
  sw.p[2] = (const float*)d_in[13];  // Wu2
  sw.p[3] = (const float*)d_in[20];  // Wp1
  sw.p[4] = (const float*)d_in[21];  // Wp2
  sw.p[5] = (const float*)d_in[36];  // Wo1
  swz_kernel<<<(SWZ_N + 255) / 256, 256, 0, stream>>>(sw, (const float*)d_in[37], wb);

  const int nrn2 = (int)((size_t)cB * cNR * cF / 2);
  cvtn_kernel<<<(nrn2 + 255) / 256, 256, 0, stream>>>(rnode, rnb, nrn2);

  cond_kernel<<<dim3(3, cB), 256, 0, stream>>>(
      tau,
      (const float*)d_in[8],  (const float*)d_in[10],
      (const float*)d_in[9],  (const float*)d_in[11],
      (const float*)d_in[16], (const float*)d_in[18],
      (const float*)d_in[17], (const float*)d_in[19],
      (const float*)d_in[24], (const float*)d_in[26],
      (const float*)d_in[25], (const float*)d_in[27],
      ws + WS_SS);

  EWb ew = { (const float*)d_in[4], (const float*)d_in[6], (const float*)d_in[7],
             (const float*)d_in[14], (const float*)d_in[15] };
  PWb pw = { (const float*)d_in[22], (const float*)d_in[23], (const float*)d_in[38],
             (const float*)d_in[39] };

  const int n4 = (int)(WS_SS / 4);
  zero_kernel<<<(n4 + 255) / 256, 256, 0, stream>>>((float4*)ws, n4);

  edge_mfma<<<dim3(cE / 64, cB), 256, 0, stream>>>(
      rnb, pnode, efeat, senders, receivers, ew, wb,
      ws + WS_SS, aggb, ws + WS_CNT);

  pnode_mfma<<<dim3(cNP / 64, cB), 256, 0, stream>>>(
      pnode, pw, wb, ws + WS_SS, aggb, ws + WS_CNT,
      (float*)d_out);
}